// Round 1
// baseline (870.728 us; speedup 1.0000x reference)
//
#include <hip/hip_runtime.h>
#include <hip/hip_bf16.h>
#include <cstdint>
#include <cstddef>

#define NPTS 16000
#define KNB  16
#define CDIM 384
#define NH   6
#define HDIM 64
#define T2C  49

static constexpr float WIN   = 6.0f;
static constexpr float QUANT = 0.24f;
static constexpr float QSCALE = 0.125f; // 64^-0.5

// ---------------------------------------------------------------- min reduce
__global__ void init_min_kernel(unsigned int* minbits) {
    if (threadIdx.x < 3) minbits[threadIdx.x] = 0x7f800000u; // +inf
}

__global__ void min_kernel(const float* __restrict__ xyz,
                           unsigned int* __restrict__ minbits) {
    float m0 = INFINITY, m1 = INFINITY, m2 = INFINITY;
    for (int i = blockIdx.x * blockDim.x + threadIdx.x; i < NPTS;
         i += gridDim.x * blockDim.x) {
        m0 = fminf(m0, xyz[i * 3 + 0]);
        m1 = fminf(m1, xyz[i * 3 + 1]);
        m2 = fminf(m2, xyz[i * 3 + 2]);
    }
#pragma unroll
    for (int off = 1; off < 64; off <<= 1) {
        m0 = fminf(m0, __shfl_xor(m0, off, 64));
        m1 = fminf(m1, __shfl_xor(m1, off, 64));
        m2 = fminf(m2, __shfl_xor(m2, off, 64));
    }
    if ((threadIdx.x & 63) == 0) {
        // xyz >= 0, so unsigned bit-pattern compare == float compare
        atomicMin(&minbits[0], __float_as_uint(m0));
        atomicMin(&minbits[1], __float_as_uint(m1));
        atomicMin(&minbits[2], __float_as_uint(m2));
    }
}

// ------------------------------------------------------------- quantize xyz
__global__ void xq_kernel(const float* __restrict__ xyz,
                          const int* __restrict__ sort_idx,
                          const unsigned int* __restrict__ minbits,
                          int* __restrict__ xq) {
    int n = blockIdx.x * blockDim.x + threadIdx.x;
    if (n >= NPTS) return;
    int orig = sort_idx[n];
#pragma unroll
    for (int t = 0; t < 3; ++t) {
        float mn = __uint_as_float(minbits[t]);
        float v  = xyz[orig * 3 + t] - mn;   // >= 0
        float md = fmodf(v, WIN);            // == np.mod for non-negative
        float q  = floorf(md / QUANT);
        xq[n * 3 + t] = (int)q;
    }
}

// --------------------------------------------------------------- f32 GEMM
// Cout[n, j] = (dot(A[g(n), :], W[j, :]) + bias[j]) * scale
// A: [*, 384] row-major (gathered by gidx if non-null), W: [384, 384] row-major
__global__ __launch_bounds__(256) void gemm_gather(
    const float* __restrict__ A, const float* __restrict__ W,
    const float* __restrict__ bias, float* __restrict__ Cout,
    const int* __restrict__ gidx, float scale) {
    const int tid = threadIdx.x;
    const int tx = tid & 15, ty = tid >> 4;
    const int j0 = blockIdx.x * 64;   // output col tile
    const int n0 = blockIdx.y * 64;   // output row tile

    __shared__ float As[16][65]; // [k][row], padded
    __shared__ float Bs[16][65];

    float acc[4][4] = {};

    for (int k0 = 0; k0 < CDIM; k0 += 16) {
#pragma unroll
        for (int pass = 0; pass < 4; ++pass) {
            int row  = (tid >> 4) + pass * 16;
            int colk = tid & 15;
            int ar   = n0 + row;
            int arow = gidx ? gidx[ar] : ar;
            As[colk][row] = A[(size_t)arow * CDIM + k0 + colk];
            Bs[colk][row] = W[(size_t)(j0 + row) * CDIM + k0 + colk];
        }
        __syncthreads();
#pragma unroll
        for (int kk = 0; kk < 16; ++kk) {
            float a[4], b[4];
#pragma unroll
            for (int i = 0; i < 4; ++i) a[i] = As[kk][ty * 4 + i];
#pragma unroll
            for (int j = 0; j < 4; ++j) b[j] = Bs[kk][tx * 4 + j];
#pragma unroll
            for (int i = 0; i < 4; ++i)
#pragma unroll
                for (int j = 0; j < 4; ++j) acc[i][j] += a[i] * b[j];
        }
        __syncthreads();
    }

#pragma unroll
    for (int i = 0; i < 4; ++i) {
        int r  = n0 + ty * 4 + i;
        int jb = j0 + tx * 4;
        float4 o;
        o.x = (acc[i][0] + bias[jb + 0]) * scale;
        o.y = (acc[i][1] + bias[jb + 1]) * scale;
        o.z = (acc[i][2] + bias[jb + 2]) * scale;
        o.w = (acc[i][3] + bias[jb + 3]) * scale;
        *(float4*)&Cout[(size_t)r * CDIM + jb] = o;
    }
}

// -------------------------------------------------- fused attention per query
// block = 384 threads (6 waves); wave h handles head h, lane = head-dim d.
__global__ __launch_bounds__(384) void attn_kernel(
    const float* __restrict__ qs, const float* __restrict__ ks,
    const float* __restrict__ vs, const int* __restrict__ xq,
    const int* __restrict__ offs, const int* __restrict__ idx1,
    const int* __restrict__ sort_idx,
    const float* __restrict__ Tq, const float* __restrict__ Tk,
    const float* __restrict__ Tv, float* __restrict__ xbuf) {
    int n = blockIdx.x;
    int h = threadIdx.x >> 6;
    int d = threadIdx.x & 63;

    __shared__ int nb[KNB];
    __shared__ int rel[KNB][3];

    int base = offs[n];
    if (threadIdx.x < KNB) {
        int p   = threadIdx.x;
        int key = idx1[base + p];
        nb[p]   = key;
#pragma unroll
        for (int t = 0; t < 3; ++t) {
            int r = xq[n * 3 + t] - xq[key * 3 + t] + 24;
            r = min(max(r, 0), T2C - 1);   // match JAX clip-mode gather
            rel[p][t] = r;
        }
    }
    __syncthreads();

    const size_t hd = (size_t)h * HDIM + d;
    float qd = qs[(size_t)n * CDIM + hd];

    float lg[KNB];
#pragma unroll
    for (int p = 0; p < KNB; ++p) {
        int key = nb[p];
        float kd = ks[(size_t)key * CDIM + hd];
        int r0 = rel[p][0], r1 = rel[p][1], r2 = rel[p][2];
        // T[(r*3+t)*NH*HDIM + h*HDIM + d]
        float tq = Tq[((r0 * 3 + 0) * NH + h) * HDIM + d]
                 + Tq[((r1 * 3 + 1) * NH + h) * HDIM + d]
                 + Tq[((r2 * 3 + 2) * NH + h) * HDIM + d];
        float tk = Tk[((r0 * 3 + 0) * NH + h) * HDIM + d]
                 + Tk[((r1 * 3 + 1) * NH + h) * HDIM + d]
                 + Tk[((r2 * 3 + 2) * NH + h) * HDIM + d];
        float partial = qd * kd + qd * tq + kd * tk;
#pragma unroll
        for (int m = 1; m < 64; m <<= 1) partial += __shfl_xor(partial, m, 64);
        lg[p] = partial;
    }

    // softmax over the 16 neighbors (replicated in every lane of the wave)
    float mx = lg[0];
#pragma unroll
    for (int p = 1; p < KNB; ++p) mx = fmaxf(mx, lg[p]);
    float s = 0.f;
#pragma unroll
    for (int p = 0; p < KNB; ++p) { lg[p] = expf(lg[p] - mx); s += lg[p]; }
    float inv = 1.f / s;

    // weighted aggregation: V plus rel-pos value tables
    float acc = 0.f;
#pragma unroll
    for (int p = 0; p < KNB; ++p) {
        float w  = lg[p] * inv;
        int  key = nb[p];
        int r0 = rel[p][0], r1 = rel[p][1], r2 = rel[p][2];
        float tv = Tv[((r0 * 3 + 0) * NH + h) * HDIM + d]
                 + Tv[((r1 * 3 + 1) * NH + h) * HDIM + d]
                 + Tv[((r2 * 3 + 2) * NH + h) * HDIM + d];
        acc += w * (vs[(size_t)key * CDIM + hd] + tv);
    }

    int dst = sort_idx[n]; // out.at[sort_idx].set(x)
    xbuf[(size_t)dst * CDIM + hd] = acc;
}

// ---------------------------------------------------------------------------
extern "C" void kernel_launch(void* const* d_in, const int* in_sizes, int n_in,
                              void* d_out, int out_size, void* d_ws,
                              size_t ws_size, hipStream_t stream) {
    const float* feats  = (const float*)d_in[0];
    const float* xyz    = (const float*)d_in[1];
    const int*   offs   = (const int*)d_in[3];
    const int*   index1 = (const int*)d_in[4];
    const int*   sortix = (const int*)d_in[5];
    const float* Wq = (const float*)d_in[6];
    const float* bq = (const float*)d_in[7];
    const float* Wk = (const float*)d_in[8];
    const float* bk = (const float*)d_in[9];
    const float* Wv = (const float*)d_in[10];
    const float* bv = (const float*)d_in[11];
    const float* Wp = (const float*)d_in[12];
    const float* bp = (const float*)d_in[13];
    const float* Tq = (const float*)d_in[14];
    const float* Tk = (const float*)d_in[15];
    const float* Tv = (const float*)d_in[16];
    float* out = (float*)d_out;

    char* ws = (char*)d_ws;
    size_t off = 0;
    auto alloc = [&](size_t bytes) -> void* {
        void* p = ws + off;
        off = (off + bytes + 255) & ~(size_t)255;
        return p;
    };
    const size_t mat_bytes = (size_t)NPTS * CDIM * sizeof(float);
    float* qs   = (float*)alloc(mat_bytes);
    float* ks   = (float*)alloc(mat_bytes);
    float* vs   = (float*)alloc(mat_bytes);
    float* xbuf = (float*)alloc(mat_bytes);
    int*   xq   = (int*)alloc((size_t)NPTS * 3 * sizeof(int));
    unsigned int* minbits = (unsigned int*)alloc(16);

    init_min_kernel<<<1, 64, 0, stream>>>(minbits);
    min_kernel<<<128, 256, 0, stream>>>(xyz, minbits);
    xq_kernel<<<(NPTS + 255) / 256, 256, 0, stream>>>(xyz, sortix, minbits, xq);

    dim3 g(CDIM / 64, NPTS / 64);
    gemm_gather<<<g, 256, 0, stream>>>(feats, Wq, bq, qs, sortix, QSCALE);
    gemm_gather<<<g, 256, 0, stream>>>(feats, Wk, bk, ks, sortix, 1.0f);
    gemm_gather<<<g, 256, 0, stream>>>(feats, Wv, bv, vs, sortix, 1.0f);

    attn_kernel<<<NPTS, 384, 0, stream>>>(qs, ks, vs, xq, offs, index1, sortix,
                                          Tq, Tk, Tv, xbuf);

    gemm_gather<<<g, 256, 0, stream>>>(xbuf, Wp, bp, out, nullptr, 1.0f);
}

// Round 2
// 341.871 us; speedup vs baseline: 2.5470x; 2.5470x over previous
//
#include <hip/hip_runtime.h>
#include <hip/hip_bf16.h>
#include <cstdint>
#include <cstddef>

#define NPTS 16000
#define KNB  16
#define CDIM 384
#define NH   6
#define HDIM 64
#define T2C  49
#define NQKV 1152   // 3*384 fused q,k,v output cols

static constexpr float WIN    = 6.0f;
static constexpr float QUANT  = 0.24f;
static constexpr float QSCALE = 0.125f; // 64^-0.5

typedef __attribute__((ext_vector_type(8))) short short8;
typedef __attribute__((ext_vector_type(4))) float floatx4;
typedef __attribute__((ext_vector_type(4))) unsigned short ushort4v;

__device__ inline unsigned short f2bf(float x) {
    unsigned int u = __float_as_uint(x);
    unsigned int r = (u + 0x7fffu + ((u >> 16) & 1u)) >> 16;
    return (unsigned short)r;
}
__device__ inline float bf2f(unsigned short b) {
    return __uint_as_float(((unsigned int)b) << 16);
}

// ---------------------------------------------------------------- min reduce
__global__ void init_min_kernel(unsigned int* minbits) {
    if (threadIdx.x < 3) minbits[threadIdx.x] = 0x7f800000u; // +inf
}

__global__ void min_kernel(const float* __restrict__ xyz,
                           unsigned int* __restrict__ minbits) {
    float m0 = INFINITY, m1 = INFINITY, m2 = INFINITY;
    for (int i = blockIdx.x * blockDim.x + threadIdx.x; i < NPTS;
         i += gridDim.x * blockDim.x) {
        m0 = fminf(m0, xyz[i * 3 + 0]);
        m1 = fminf(m1, xyz[i * 3 + 1]);
        m2 = fminf(m2, xyz[i * 3 + 2]);
    }
#pragma unroll
    for (int off = 1; off < 64; off <<= 1) {
        m0 = fminf(m0, __shfl_xor(m0, off, 64));
        m1 = fminf(m1, __shfl_xor(m1, off, 64));
        m2 = fminf(m2, __shfl_xor(m2, off, 64));
    }
    if ((threadIdx.x & 63) == 0) {
        atomicMin(&minbits[0], __float_as_uint(m0)); // xyz >= 0
        atomicMin(&minbits[1], __float_as_uint(m1));
        atomicMin(&minbits[2], __float_as_uint(m2));
    }
}

// ------------------------------------------------------------- quantize xyz
__global__ void xq_kernel(const float* __restrict__ xyz,
                          const int* __restrict__ sort_idx,
                          const unsigned int* __restrict__ minbits,
                          int* __restrict__ xq) {
    int n = blockIdx.x * blockDim.x + threadIdx.x;
    if (n >= NPTS) return;
    int orig = sort_idx[n];
#pragma unroll
    for (int t = 0; t < 3; ++t) {
        float mn = __uint_as_float(minbits[t]);
        float v  = xyz[orig * 3 + t] - mn;   // >= 0
        float md = fmodf(v, WIN);            // == np.mod for non-negative
        float q  = floorf(md / QUANT);
        xq[n * 3 + t] = (int)q;
    }
}

// ------------------------------------------------- gather+convert feats->bf16
__global__ void gather_bf16_kernel(const float* __restrict__ feats,
                                   const int* __restrict__ sortix,
                                   unsigned short* __restrict__ out) {
    int i = blockIdx.x * blockDim.x + threadIdx.x; // group of 4 elements
    if (i >= NPTS * CDIM / 4) return;
    int n  = i / (CDIM / 4);
    int c4 = (i % (CDIM / 4)) * 4;
    const float4 v = *(const float4*)&feats[(size_t)sortix[n] * CDIM + c4];
    ushort4v o;
    o.x = f2bf(v.x); o.y = f2bf(v.y); o.z = f2bf(v.z); o.w = f2bf(v.w);
    *(ushort4v*)&out[(size_t)n * CDIM + c4] = o;
}

// --------------------------------------------------- pack W(q|k|v) -> bf16
__global__ void pack_w_kernel(const float* __restrict__ Wq,
                              const float* __restrict__ Wk,
                              const float* __restrict__ Wv,
                              const float* __restrict__ bq,
                              const float* __restrict__ bk,
                              const float* __restrict__ bv,
                              unsigned short* __restrict__ Wcat,
                              float* __restrict__ bcat) {
    int i = blockIdx.x * blockDim.x + threadIdx.x;
    if (i < NQKV)
        bcat[i] = (i < 384) ? bq[i] : (i < 768) ? bk[i - 384] : bv[i - 768];
    for (int e = i; e < NQKV * CDIM; e += gridDim.x * blockDim.x) {
        int j = e / CDIM, k = e % CDIM;
        float v = (j < 384)   ? Wq[j * CDIM + k]
                : (j < 768)   ? Wk[(j - 384) * CDIM + k]
                              : Wv[(j - 768) * CDIM + k];
        Wcat[e] = f2bf(v);
    }
}

// ---------------------------------------------------- fused QKV bf16 MFMA GEMM
// C[n, j] = dot(Abf[n,:], Wcat[j,:]) + bcat[j];  n<16000, j<1152, K=384
// epilogue scatters to head-major qh (f32, *SCALE) / kh, vh (bf16)
__global__ __launch_bounds__(256) void gemm_qkv(
    const unsigned short* __restrict__ Abf,
    const unsigned short* __restrict__ Wcat,
    const float* __restrict__ bcat,
    float* __restrict__ qh, unsigned short* __restrict__ kh,
    unsigned short* __restrict__ vh) {
    __shared__ unsigned short As[128 * 64];
    __shared__ unsigned short Bs[128 * 64];
    const int tid  = threadIdx.x;
    const int lane = tid & 63;
    const int w    = tid >> 6;
    const int wm   = w >> 1, wn = w & 1;
    const int m0   = blockIdx.x * 128;
    const int jn0  = blockIdx.y * 128;

    floatx4 acc[4][4];
#pragma unroll
    for (int i = 0; i < 4; ++i)
#pragma unroll
        for (int j = 0; j < 4; ++j) acc[i][j] = (floatx4)0.0f;

    for (int kt = 0; kt < 6; ++kt) {
        const int k0 = kt * 64;
#pragma unroll
        for (int q = 0; q < 4; ++q) {
            const int s    = w * 4 + q;            // 1KB segment id
            const int row  = s * 8 + (lane >> 3);  // matches base+lane*16 layout
            const int col  = (lane & 7) * 8;
            const unsigned short* ga = Abf  + (size_t)(m0  + row) * CDIM + k0 + col;
            const unsigned short* gb = Wcat + (size_t)(jn0 + row) * CDIM + k0 + col;
            __builtin_amdgcn_global_load_lds(
                (const __attribute__((address_space(1))) void*)ga,
                (__attribute__((address_space(3))) void*)&As[s * 512], 16, 0, 0);
            __builtin_amdgcn_global_load_lds(
                (const __attribute__((address_space(1))) void*)gb,
                (__attribute__((address_space(3))) void*)&Bs[s * 512], 16, 0, 0);
        }
        __syncthreads();
#pragma unroll
        for (int ks = 0; ks < 2; ++ks) {
            short8 a[4], b[4];
#pragma unroll
            for (int mi = 0; mi < 4; ++mi) {
                int row = wm * 64 + mi * 16 + (lane & 15);
                a[mi] = *(const short8*)&As[row * 64 + ks * 32 + (lane >> 4) * 8];
            }
#pragma unroll
            for (int ni = 0; ni < 4; ++ni) {
                int jr = wn * 64 + ni * 16 + (lane & 15);
                b[ni] = *(const short8*)&Bs[jr * 64 + ks * 32 + (lane >> 4) * 8];
            }
#pragma unroll
            for (int mi = 0; mi < 4; ++mi)
#pragma unroll
                for (int ni = 0; ni < 4; ++ni)
                    acc[mi][ni] = __builtin_amdgcn_mfma_f32_16x16x32_bf16(
                        a[mi], b[ni], acc[mi][ni], 0, 0, 0);
        }
        __syncthreads();
    }

#pragma unroll
    for (int mi = 0; mi < 4; ++mi)
#pragma unroll
        for (int ni = 0; ni < 4; ++ni) {
            int j = jn0 + wn * 64 + ni * 16 + (lane & 15);
            int which = j / CDIM;
            int c = j - which * CDIM;
            int h = c >> 6, d = c & 63;
            float bias = bcat[j];
#pragma unroll
            for (int r = 0; r < 4; ++r) {
                int n = m0 + wm * 64 + mi * 16 + (lane >> 4) * 4 + r;
                float val = acc[mi][ni][r] + bias;
                size_t o = ((size_t)h * NPTS + n) * HDIM + d;
                if (which == 0)      qh[o] = val * QSCALE;
                else if (which == 1) kh[o] = f2bf(val);
                else                 vh[o] = f2bf(val);
            }
        }
}

// -------------------------------------------------- fused attention per query
// grid (NPTS/4, NH), block 256 = 4 waves; wave = one query, head = blockIdx.y.
// lane = pp*16 + c : pp selects pair within group-of-4, c selects d-chunk (4 d).
__global__ __launch_bounds__(256) void attn_kernel(
    const float* __restrict__ qh, const unsigned short* __restrict__ kh,
    const unsigned short* __restrict__ vh, const int* __restrict__ xq,
    const int* __restrict__ idx1, const int* __restrict__ sortix,
    const float* __restrict__ Tq, const float* __restrict__ Tk,
    const float* __restrict__ Tv, float* __restrict__ xbuf) {
    const int h    = blockIdx.y;
    const int n    = blockIdx.x * 4 + (threadIdx.x >> 6);
    const int lane = threadIdx.x & 63;
    const int pp   = lane >> 4, c = lane & 15;

    const float4 q4 = *(const float4*)&qh[((size_t)h * NPTS + n) * HDIM + c * 4];

    const int xqn0 = xq[n * 3 + 0], xqn1 = xq[n * 3 + 1], xqn2 = xq[n * 3 + 2];

    float lg[4];
    int keyg[4], r0g[4], r1g[4], r2g[4];
#pragma unroll
    for (int g = 0; g < 4; ++g) {
        const int p   = g * 4 + pp;
        const int key = idx1[n * KNB + p];
        keyg[g] = key;
        int r0 = xqn0 - xq[key * 3 + 0] + 24; r0 = min(max(r0, 0), T2C - 1);
        int r1 = xqn1 - xq[key * 3 + 1] + 24; r1 = min(max(r1, 0), T2C - 1);
        int r2 = xqn2 - xq[key * 3 + 2] + 24; r2 = min(max(r2, 0), T2C - 1);
        r0g[g] = r0; r1g[g] = r1; r2g[g] = r2;

        const ushort4v k4 = *(const ushort4v*)&kh[((size_t)h * NPTS + key) * HDIM + c * 4];
        const float kf0 = bf2f(k4.x), kf1 = bf2f(k4.y), kf2 = bf2f(k4.z), kf3 = bf2f(k4.w);

        const float4 a0 = *(const float4*)&Tq[((r0 * 3 + 0) * NH + h) * HDIM + c * 4];
        const float4 a1 = *(const float4*)&Tq[((r1 * 3 + 1) * NH + h) * HDIM + c * 4];
        const float4 a2 = *(const float4*)&Tq[((r2 * 3 + 2) * NH + h) * HDIM + c * 4];
        const float4 b0 = *(const float4*)&Tk[((r0 * 3 + 0) * NH + h) * HDIM + c * 4];
        const float4 b1 = *(const float4*)&Tk[((r1 * 3 + 1) * NH + h) * HDIM + c * 4];
        const float4 b2 = *(const float4*)&Tk[((r2 * 3 + 2) * NH + h) * HDIM + c * 4];
        const float tqx = a0.x + a1.x + a2.x, tqy = a0.y + a1.y + a2.y,
                    tqz = a0.z + a1.z + a2.z, tqw = a0.w + a1.w + a2.w;
        const float tkx = b0.x + b1.x + b2.x, tky = b0.y + b1.y + b2.y,
                    tkz = b0.z + b1.z + b2.z, tkw = b0.w + b1.w + b2.w;
        // q·k + q·Tqsum + k·Tksum
        float part = q4.x * (kf0 + tqx) + kf0 * tkx;
        part      += q4.y * (kf1 + tqy) + kf1 * tky;
        part      += q4.z * (kf2 + tqz) + kf2 * tkz;
        part      += q4.w * (kf3 + tqw) + kf3 * tkw;
        lg[g] = part;
    }
    // reduce each pair's partial over the 16 c-lanes (segmented butterfly)
#pragma unroll
    for (int m = 1; m <= 8; m <<= 1) {
#pragma unroll
        for (int g = 0; g < 4; ++g) lg[g] += __shfl_xor(lg[g], m, 64);
    }
    // softmax over 16 pairs (4 in-lane × 4 pp-groups)
    float mx = fmaxf(fmaxf(lg[0], lg[1]), fmaxf(lg[2], lg[3]));
    mx = fmaxf(mx, __shfl_xor(mx, 16, 64));
    mx = fmaxf(mx, __shfl_xor(mx, 32, 64));
    float e[4], s = 0.f;
#pragma unroll
    for (int g = 0; g < 4; ++g) { e[g] = expf(lg[g] - mx); s += e[g]; }
    s += __shfl_xor(s, 16, 64);
    s += __shfl_xor(s, 32, 64);
    const float inv = 1.f / s;

    // weighted V + Tv aggregation
    float xa0 = 0.f, xa1 = 0.f, xa2 = 0.f, xa3 = 0.f;
#pragma unroll
    for (int g = 0; g < 4; ++g) {
        const float wgt = e[g] * inv;
        const ushort4v v4 =
            *(const ushort4v*)&vh[((size_t)h * NPTS + keyg[g]) * HDIM + c * 4];
        const float4 t0 = *(const float4*)&Tv[((r0g[g] * 3 + 0) * NH + h) * HDIM + c * 4];
        const float4 t1 = *(const float4*)&Tv[((r1g[g] * 3 + 1) * NH + h) * HDIM + c * 4];
        const float4 t2 = *(const float4*)&Tv[((r2g[g] * 3 + 2) * NH + h) * HDIM + c * 4];
        xa0 += wgt * (bf2f(v4.x) + t0.x + t1.x + t2.x);
        xa1 += wgt * (bf2f(v4.y) + t0.y + t1.y + t2.y);
        xa2 += wgt * (bf2f(v4.z) + t0.z + t1.z + t2.z);
        xa3 += wgt * (bf2f(v4.w) + t0.w + t1.w + t2.w);
    }
#pragma unroll
    for (int m = 16; m <= 32; m <<= 1) {
        xa0 += __shfl_xor(xa0, m, 64);
        xa1 += __shfl_xor(xa1, m, 64);
        xa2 += __shfl_xor(xa2, m, 64);
        xa3 += __shfl_xor(xa3, m, 64);
    }
    if (pp == 0) {
        const int dst = sortix[n]; // unsort
        float4 o; o.x = xa0; o.y = xa1; o.z = xa2; o.w = xa3;
        *(float4*)&xbuf[(size_t)dst * CDIM + h * HDIM + c * 4] = o;
    }
}

// --------------------------------------------------------------- f32 GEMM
// (final projection) Cout[n,j] = dot(A[n,:], W[j,:]) + bias[j]
__global__ __launch_bounds__(256) void gemm_gather(
    const float* __restrict__ A, const float* __restrict__ W,
    const float* __restrict__ bias, float* __restrict__ Cout,
    const int* __restrict__ gidx, float scale) {
    const int tid = threadIdx.x;
    const int tx = tid & 15, ty = tid >> 4;
    const int j0 = blockIdx.x * 64;
    const int n0 = blockIdx.y * 64;

    __shared__ float As[16][65];
    __shared__ float Bs[16][65];

    float acc[4][4] = {};

    for (int k0 = 0; k0 < CDIM; k0 += 16) {
#pragma unroll
        for (int pass = 0; pass < 4; ++pass) {
            int row  = (tid >> 4) + pass * 16;
            int colk = tid & 15;
            int ar   = n0 + row;
            int arow = gidx ? gidx[ar] : ar;
            As[colk][row] = A[(size_t)arow * CDIM + k0 + colk];
            Bs[colk][row] = W[(size_t)(j0 + row) * CDIM + k0 + colk];
        }
        __syncthreads();
#pragma unroll
        for (int kk = 0; kk < 16; ++kk) {
            float a[4], b[4];
#pragma unroll
            for (int i = 0; i < 4; ++i) a[i] = As[kk][ty * 4 + i];
#pragma unroll
            for (int j = 0; j < 4; ++j) b[j] = Bs[kk][tx * 4 + j];
#pragma unroll
            for (int i = 0; i < 4; ++i)
#pragma unroll
                for (int j = 0; j < 4; ++j) acc[i][j] += a[i] * b[j];
        }
        __syncthreads();
    }

#pragma unroll
    for (int i = 0; i < 4; ++i) {
        int r  = n0 + ty * 4 + i;
        int jb = j0 + tx * 4;
        float4 o;
        o.x = (acc[i][0] + bias[jb + 0]) * scale;
        o.y = (acc[i][1] + bias[jb + 1]) * scale;
        o.z = (acc[i][2] + bias[jb + 2]) * scale;
        o.w = (acc[i][3] + bias[jb + 3]) * scale;
        *(float4*)&Cout[(size_t)r * CDIM + jb] = o;
    }
}

// ---------------------------------------------------------------------------
extern "C" void kernel_launch(void* const* d_in, const int* in_sizes, int n_in,
                              void* d_out, int out_size, void* d_ws,
                              size_t ws_size, hipStream_t stream) {
    const float* feats  = (const float*)d_in[0];
    const float* xyz    = (const float*)d_in[1];
    const int*   index1 = (const int*)d_in[4];
    const int*   sortix = (const int*)d_in[5];
    const float* Wq = (const float*)d_in[6];
    const float* bq = (const float*)d_in[7];
    const float* Wk = (const float*)d_in[8];
    const float* bk = (const float*)d_in[9];
    const float* Wv = (const float*)d_in[10];
    const float* bv = (const float*)d_in[11];
    const float* Wp = (const float*)d_in[12];
    const float* bp = (const float*)d_in[13];
    const float* Tq = (const float*)d_in[14];
    const float* Tk = (const float*)d_in[15];
    const float* Tv = (const float*)d_in[16];
    float* out = (float*)d_out;

    char* ws = (char*)d_ws;
    size_t off = 0;
    auto alloc = [&](size_t bytes) -> void* {
        void* p = ws + off;
        off = (off + bytes + 255) & ~(size_t)255;
        return p;
    };
    unsigned short* featsbf = (unsigned short*)alloc((size_t)NPTS * CDIM * 2);
    unsigned short* Wcat    = (unsigned short*)alloc((size_t)NQKV * CDIM * 2);
    float*          bcat    = (float*)alloc(NQKV * sizeof(float));
    float*          qh      = (float*)alloc((size_t)NH * NPTS * HDIM * 4);
    unsigned short* kh      = (unsigned short*)alloc((size_t)NH * NPTS * HDIM * 2);
    unsigned short* vh      = (unsigned short*)alloc((size_t)NH * NPTS * HDIM * 2);
    float*          xbuf    = (float*)alloc((size_t)NPTS * CDIM * 4);
    int*            xq      = (int*)alloc((size_t)NPTS * 3 * sizeof(int));
    unsigned int*   minbits = (unsigned int*)alloc(16);

    init_min_kernel<<<1, 64, 0, stream>>>(minbits);
    min_kernel<<<128, 256, 0, stream>>>(xyz, minbits);
    xq_kernel<<<(NPTS + 255) / 256, 256, 0, stream>>>(xyz, sortix, minbits, xq);

    gather_bf16_kernel<<<(NPTS * CDIM / 4 + 255) / 256, 256, 0, stream>>>(
        feats, sortix, featsbf);
    pack_w_kernel<<<(NQKV * CDIM + 255) / 256, 256, 0, stream>>>(
        Wq, Wk, Wv, bq, bk, bv, Wcat, bcat);

    dim3 gq(NPTS / 128, NQKV / 128);
    gemm_qkv<<<gq, 256, 0, stream>>>(featsbf, Wcat, bcat, qh, kh, vh);

    dim3 ga(NPTS / 4, NH);
    attn_kernel<<<ga, 256, 0, stream>>>(qh, kh, vh, xq, index1, sortix,
                                        Tq, Tk, Tv, xbuf);

    dim3 gp(CDIM / 64, NPTS / 64);
    gemm_gather<<<gp, 256, 0, stream>>>(xbuf, Wp, bp, out, nullptr, 1.0f);
}

// Round 3
// 290.988 us; speedup vs baseline: 2.9923x; 1.1749x over previous
//
#include <hip/hip_runtime.h>
#include <hip/hip_bf16.h>
#include <cstdint>
#include <cstddef>

#define NPTS 16000
#define KNB  16
#define CDIM 384
#define NH   6
#define HDIM 64
#define T2C  49
#define NQKV 1152            // 3*384 fused q,k,v output cols
#define NL3T 147             // 49*3 table rows
#define DSTR 882             // 147*6 : per-point dq/dk row stride (elems)

static constexpr float WIN    = 6.0f;
static constexpr float QUANT  = 0.24f;
static constexpr float QSCALE = 0.125f; // 64^-0.5

typedef __attribute__((ext_vector_type(8))) short short8;
typedef __attribute__((ext_vector_type(4))) float floatx4;
typedef __attribute__((ext_vector_type(4))) unsigned short ushort4v;

__device__ inline unsigned short f2bf(float x) {
    unsigned int u = __float_as_uint(x);
    unsigned int r = (u + 0x7fffu + ((u >> 16) & 1u)) >> 16;
    return (unsigned short)r;
}
__device__ inline float bf2f(unsigned short b) {
    return __uint_as_float(((unsigned int)b) << 16);
}

// ---------------------------------------------------------------- min reduce
__global__ void init_min_kernel(unsigned int* minbits) {
    if (threadIdx.x < 3) minbits[threadIdx.x] = 0x7f800000u; // +inf
}

__global__ void min_kernel(const float* __restrict__ xyz,
                           unsigned int* __restrict__ minbits) {
    float m0 = INFINITY, m1 = INFINITY, m2 = INFINITY;
    for (int i = blockIdx.x * blockDim.x + threadIdx.x; i < NPTS;
         i += gridDim.x * blockDim.x) {
        m0 = fminf(m0, xyz[i * 3 + 0]);
        m1 = fminf(m1, xyz[i * 3 + 1]);
        m2 = fminf(m2, xyz[i * 3 + 2]);
    }
#pragma unroll
    for (int off = 1; off < 64; off <<= 1) {
        m0 = fminf(m0, __shfl_xor(m0, off, 64));
        m1 = fminf(m1, __shfl_xor(m1, off, 64));
        m2 = fminf(m2, __shfl_xor(m2, off, 64));
    }
    if ((threadIdx.x & 63) == 0) {
        atomicMin(&minbits[0], __float_as_uint(m0)); // xyz >= 0
        atomicMin(&minbits[1], __float_as_uint(m1));
        atomicMin(&minbits[2], __float_as_uint(m2));
    }
}

// ------------------------------------------------------------- quantize xyz
__global__ void xq_kernel(const float* __restrict__ xyz,
                          const int* __restrict__ sort_idx,
                          const unsigned int* __restrict__ minbits,
                          int* __restrict__ xq) {
    int n = blockIdx.x * blockDim.x + threadIdx.x;
    if (n >= NPTS) return;
    int orig = sort_idx[n];
#pragma unroll
    for (int t = 0; t < 3; ++t) {
        float mn = __uint_as_float(minbits[t]);
        float v  = xyz[orig * 3 + t] - mn;   // >= 0
        float md = fmodf(v, WIN);            // == np.mod for non-negative
        float q  = floorf(md / QUANT);
        xq[n * 3 + t] = (int)q;
    }
}

// ----------------------------------------------- pack (key, rel0..2) per pair
__global__ void relpack_kernel(const int* __restrict__ idx1,
                               const int* __restrict__ xq,
                               unsigned int* __restrict__ pairs) {
    int m = blockIdx.x * blockDim.x + threadIdx.x;
    if (m >= NPTS * KNB) return;
    int n = m >> 4;
    int key = idx1[m];
    int r0 = xq[n * 3 + 0] - xq[key * 3 + 0] + 24; r0 = min(max(r0, 0), T2C - 1);
    int r1 = xq[n * 3 + 1] - xq[key * 3 + 1] + 24; r1 = min(max(r1, 0), T2C - 1);
    int r2 = xq[n * 3 + 2] - xq[key * 3 + 2] + 24; r2 = min(max(r2, 0), T2C - 1);
    pairs[m] = (unsigned)key | ((unsigned)r0 << 14) | ((unsigned)r1 << 20) |
               ((unsigned)r2 << 26);
}

// ------------------------------------------------- gather+convert feats->bf16
__global__ void gather_bf16_kernel(const float* __restrict__ feats,
                                   const int* __restrict__ sortix,
                                   unsigned short* __restrict__ out) {
    int i = blockIdx.x * blockDim.x + threadIdx.x; // group of 4 elements
    if (i >= NPTS * CDIM / 4) return;
    int n  = i / (CDIM / 4);
    int c4 = (i % (CDIM / 4)) * 4;
    const float4 v = *(const float4*)&feats[(size_t)sortix[n] * CDIM + c4];
    ushort4v o;
    o.x = f2bf(v.x); o.y = f2bf(v.y); o.z = f2bf(v.z); o.w = f2bf(v.w);
    *(ushort4v*)&out[(size_t)n * CDIM + c4] = o;
}

// --------------------------------------------- pack W(q|k|v|p) -> bf16, biases
__global__ void pack_w_kernel(const float* __restrict__ Wq,
                              const float* __restrict__ Wk,
                              const float* __restrict__ Wv,
                              const float* __restrict__ Wp,
                              const float* __restrict__ bq,
                              const float* __restrict__ bk,
                              const float* __restrict__ bv,
                              const float* __restrict__ bp,
                              unsigned short* __restrict__ Wcat,
                              float* __restrict__ bcat) {
    int i = blockIdx.x * blockDim.x + threadIdx.x;
    if (i < NQKV + CDIM)
        bcat[i] = (i < 384) ? bq[i] : (i < 768) ? bk[i - 384]
                : (i < 1152) ? bv[i - 768] : bp[i - 1152];
    if (i >= (NQKV + CDIM) * CDIM) return;
    int j = i / CDIM, k = i % CDIM;
    float v = (j < 384)  ? Wq[j * CDIM + k]
            : (j < 768)  ? Wk[(j - 384) * CDIM + k]
            : (j < 1152) ? Wv[(j - 768) * CDIM + k]
                         : Wp[(j - 1152) * CDIM + k];
    Wcat[i] = f2bf(v);
}

// ----------------------------------------------------------- Tv table -> bf16
__global__ void tvpack_kernel(const float* __restrict__ Tv,
                              unsigned short* __restrict__ Tvbf) {
    int i = blockIdx.x * blockDim.x + threadIdx.x;
    if (i < NL3T * NH * HDIM) Tvbf[i] = f2bf(Tv[i]);
}

// ------------------------------------------------------ fused bf16 MFMA GEMM
// mode 0: A=featsbf [16000x384], W rows 0..1151  -> qbf (bf16,*SCALE), kh, vh
// mode 1: A=xb      [16000x384], W rows 1152..   -> outf (f32 + bias)
__global__ __launch_bounds__(256) void gemm_fused(
    const unsigned short* __restrict__ Abf,
    const unsigned short* __restrict__ Wrows,   // pre-offset
    const float* __restrict__ bias,             // pre-offset
    int mode,
    unsigned short* __restrict__ qb, unsigned short* __restrict__ kb,
    unsigned short* __restrict__ vb, float* __restrict__ outf) {
    __shared__ unsigned short As[128 * 64];
    __shared__ unsigned short Bs[128 * 64];
    const int tid  = threadIdx.x;
    const int lane = tid & 63;
    const int w    = tid >> 6;
    const int wm   = w >> 1, wn = w & 1;
    const int m0   = blockIdx.x * 128;
    const int jn0  = blockIdx.y * 128;

    floatx4 acc[4][4];
#pragma unroll
    for (int i = 0; i < 4; ++i)
#pragma unroll
        for (int j = 0; j < 4; ++j) acc[i][j] = (floatx4)0.0f;

    for (int kt = 0; kt < 6; ++kt) {
        const int k0 = kt * 64;
#pragma unroll
        for (int q = 0; q < 4; ++q) {
            const int s    = w * 4 + q;            // 1KB segment id
            const int row  = s * 8 + (lane >> 3);
            const int col  = (lane & 7) * 8;
            const unsigned short* ga = Abf   + (size_t)(m0  + row) * CDIM + k0 + col;
            const unsigned short* gb = Wrows + (size_t)(jn0 + row) * CDIM + k0 + col;
            __builtin_amdgcn_global_load_lds(
                (const __attribute__((address_space(1))) void*)ga,
                (__attribute__((address_space(3))) void*)&As[s * 512], 16, 0, 0);
            __builtin_amdgcn_global_load_lds(
                (const __attribute__((address_space(1))) void*)gb,
                (__attribute__((address_space(3))) void*)&Bs[s * 512], 16, 0, 0);
        }
        __syncthreads();
#pragma unroll
        for (int ks = 0; ks < 2; ++ks) {
            short8 a[4], b[4];
#pragma unroll
            for (int mi = 0; mi < 4; ++mi) {
                int row = wm * 64 + mi * 16 + (lane & 15);
                a[mi] = *(const short8*)&As[row * 64 + ks * 32 + (lane >> 4) * 8];
            }
#pragma unroll
            for (int ni = 0; ni < 4; ++ni) {
                int jr = wn * 64 + ni * 16 + (lane & 15);
                b[ni] = *(const short8*)&Bs[jr * 64 + ks * 32 + (lane >> 4) * 8];
            }
#pragma unroll
            for (int mi = 0; mi < 4; ++mi)
#pragma unroll
                for (int ni = 0; ni < 4; ++ni)
                    acc[mi][ni] = __builtin_amdgcn_mfma_f32_16x16x32_bf16(
                        a[mi], b[ni], acc[mi][ni], 0, 0, 0);
        }
        __syncthreads();
    }

#pragma unroll
    for (int mi = 0; mi < 4; ++mi)
#pragma unroll
        for (int ni = 0; ni < 4; ++ni) {
            int j = jn0 + wn * 64 + ni * 16 + (lane & 15);
            float bsv = bias[j];
            if (mode == 0) {
                int which = j / CDIM;
                int c = j - which * CDIM;
                int h = c >> 6, d = c & 63;
#pragma unroll
                for (int r = 0; r < 4; ++r) {
                    int n = m0 + wm * 64 + mi * 16 + (lane >> 4) * 4 + r;
                    float val = acc[mi][ni][r] + bsv;
                    size_t o = ((size_t)h * NPTS + n) * HDIM + d;
                    if (which == 0)      qb[o] = f2bf(val * QSCALE);
                    else if (which == 1) kb[o] = f2bf(val);
                    else                 vb[o] = f2bf(val);
                }
            } else {
#pragma unroll
                for (int r = 0; r < 4; ++r) {
                    int n = m0 + wm * 64 + mi * 16 + (lane >> 4) * 4 + r;
                    outf[(size_t)n * CDIM + j] = acc[mi][ni][r] + bsv;
                }
            }
        }
}

// ----------------------------------- dq/dk table-dot GEMM  [N x 64]x[64 x 147]
// X[n][j][h] (bf16) = A[h][n][:] . T[(j*6+h)*64 + :]   for j < 147
__global__ __launch_bounds__(256) void dqdk_kernel(
    const unsigned short* __restrict__ qbf, const unsigned short* __restrict__ kh,
    const float* __restrict__ Tq, const float* __restrict__ Tk,
    unsigned short* __restrict__ dq2, unsigned short* __restrict__ dk2) {
    const int h   = blockIdx.y;
    const bool isk = blockIdx.z != 0;
    const unsigned short* A = isk ? kh : qbf;
    const float* T          = isk ? Tk : Tq;
    unsigned short* X       = isk ? dk2 : dq2;

    const int lane  = threadIdx.x & 63;
    const int w     = threadIdx.x >> 6;
    const int m0    = blockIdx.x * 128 + w * 32;
    const int chunk = lane >> 4;
    const int cl    = lane & 15;

    floatx4 acc[2][10];
#pragma unroll
    for (int mi = 0; mi < 2; ++mi)
#pragma unroll
        for (int ni = 0; ni < 10; ++ni) acc[mi][ni] = (floatx4)0.0f;

#pragma unroll
    for (int ks = 0; ks < 2; ++ks) {
        short8 a[2];
#pragma unroll
        for (int mi = 0; mi < 2; ++mi)
            a[mi] = *(const short8*)&A[((size_t)h * NPTS + m0 + mi * 16 + cl) * HDIM +
                                       ks * 32 + chunk * 8];
#pragma unroll
        for (int ni = 0; ni < 10; ++ni) {
            int j = ni * 16 + cl;
            short8 b = (short8)0;
            if (j < NL3T) {
                const float* tp = &T[(size_t)(j * NH + h) * HDIM + ks * 32 + chunk * 8];
                float4 f0 = *(const float4*)tp;
                float4 f1 = *(const float4*)(tp + 4);
                b[0] = (short)f2bf(f0.x); b[1] = (short)f2bf(f0.y);
                b[2] = (short)f2bf(f0.z); b[3] = (short)f2bf(f0.w);
                b[4] = (short)f2bf(f1.x); b[5] = (short)f2bf(f1.y);
                b[6] = (short)f2bf(f1.z); b[7] = (short)f2bf(f1.w);
            }
#pragma unroll
            for (int mi = 0; mi < 2; ++mi)
                acc[mi][ni] = __builtin_amdgcn_mfma_f32_16x16x32_bf16(
                    a[mi], b, acc[mi][ni], 0, 0, 0);
        }
    }
#pragma unroll
    for (int mi = 0; mi < 2; ++mi)
#pragma unroll
        for (int ni = 0; ni < 10; ++ni) {
            int j = ni * 16 + cl;
            if (j >= NL3T) continue;
#pragma unroll
            for (int r = 0; r < 4; ++r) {
                int n = m0 + mi * 16 + chunk * 4 + r;
                X[(size_t)n * DSTR + j * 6 + h] = f2bf(acc[mi][ni][r]);
            }
        }
}

// -------------------------------------------------- fused attention per query
// grid NPTS, block 384 = 6 waves; wave h = head h of query blockIdx.x.
// lane = pp*16 + c : pp selects pair-in-group, c selects d-chunk (4 d).
__global__ __launch_bounds__(384) void attn_kernel(
    const unsigned short* __restrict__ qbf, const unsigned short* __restrict__ kh,
    const unsigned short* __restrict__ vh,
    const unsigned int* __restrict__ pairs,
    const unsigned short* __restrict__ dq2, const unsigned short* __restrict__ dk2,
    const unsigned short* __restrict__ Tvbf,
    const int* __restrict__ sortix,
    unsigned short* __restrict__ xb) {
    const int n    = blockIdx.x;
    const int h    = threadIdx.x >> 6;
    const int lane = threadIdx.x & 63;
    const int pp   = lane >> 4, c = lane & 15;

    const ushort4v q4 = *(const ushort4v*)&qbf[((size_t)h * NPTS + n) * HDIM + c * 4];
    const float qx = bf2f(q4.x), qy = bf2f(q4.y), qz = bf2f(q4.z), qw = bf2f(q4.w);

    const unsigned short* dqb = dq2 + (size_t)n * DSTR + h;

    unsigned int pv[4];
#pragma unroll
    for (int g = 0; g < 4; ++g) pv[g] = pairs[n * KNB + g * 4 + pp];

    int keyg[4], j0g[4], j1g[4], j2g[4];
#pragma unroll
    for (int g = 0; g < 4; ++g) {
        keyg[g] = (int)(pv[g] & 0x3FFFu);
        j0g[g]  = (int)((pv[g] >> 14) & 63u) * 18;
        j1g[g]  = (int)((pv[g] >> 20) & 63u) * 18 + 6;
        j2g[g]  = (int)(pv[g] >> 26) * 18 + 12;
    }

    float tab[4];
#pragma unroll
    for (int g = 0; g < 4; ++g) {
        const unsigned short* dkb = dk2 + (size_t)keyg[g] * DSTR + h;
        tab[g] = bf2f(dqb[j0g[g]]) + bf2f(dqb[j1g[g]]) + bf2f(dqb[j2g[g]]) +
                 bf2f(dkb[j0g[g]]) + bf2f(dkb[j1g[g]]) + bf2f(dkb[j2g[g]]);
    }

    float lg[4];
#pragma unroll
    for (int g = 0; g < 4; ++g) {
        const ushort4v k4 =
            *(const ushort4v*)&kh[((size_t)h * NPTS + keyg[g]) * HDIM + c * 4];
        lg[g] = qx * bf2f(k4.x) + qy * bf2f(k4.y) + qz * bf2f(k4.z) + qw * bf2f(k4.w);
    }
#pragma unroll
    for (int m = 1; m <= 8; m <<= 1)
#pragma unroll
        for (int g = 0; g < 4; ++g) lg[g] += __shfl_xor(lg[g], m, 64);
#pragma unroll
    for (int g = 0; g < 4; ++g) lg[g] += tab[g];

    // softmax over 16 pairs (4 in-lane x 4 pp-groups)
    float mx = fmaxf(fmaxf(lg[0], lg[1]), fmaxf(lg[2], lg[3]));
    mx = fmaxf(mx, __shfl_xor(mx, 16, 64));
    mx = fmaxf(mx, __shfl_xor(mx, 32, 64));
    float e[4], s = 0.f;
#pragma unroll
    for (int g = 0; g < 4; ++g) { e[g] = expf(lg[g] - mx); s += e[g]; }
    s += __shfl_xor(s, 16, 64);
    s += __shfl_xor(s, 32, 64);
    const float inv = 1.f / s;

    float xa0 = 0.f, xa1 = 0.f, xa2 = 0.f, xa3 = 0.f;
#pragma unroll
    for (int g = 0; g < 4; ++g) {
        const float wgt = e[g] * inv;
        const ushort4v v4 =
            *(const ushort4v*)&vh[((size_t)h * NPTS + keyg[g]) * HDIM + c * 4];
        const ushort4v t0 = *(const ushort4v*)&Tvbf[(size_t)(j0g[g] + h) * HDIM + c * 4];
        const ushort4v t1 = *(const ushort4v*)&Tvbf[(size_t)(j1g[g] + h) * HDIM + c * 4];
        const ushort4v t2 = *(const ushort4v*)&Tvbf[(size_t)(j2g[g] + h) * HDIM + c * 4];
        xa0 += wgt * (bf2f(v4.x) + bf2f(t0.x) + bf2f(t1.x) + bf2f(t2.x));
        xa1 += wgt * (bf2f(v4.y) + bf2f(t0.y) + bf2f(t1.y) + bf2f(t2.y));
        xa2 += wgt * (bf2f(v4.z) + bf2f(t0.z) + bf2f(t1.z) + bf2f(t2.z));
        xa3 += wgt * (bf2f(v4.w) + bf2f(t0.w) + bf2f(t1.w) + bf2f(t2.w));
    }
#pragma unroll
    for (int m = 16; m <= 32; m <<= 1) {
        xa0 += __shfl_xor(xa0, m, 64);
        xa1 += __shfl_xor(xa1, m, 64);
        xa2 += __shfl_xor(xa2, m, 64);
        xa3 += __shfl_xor(xa3, m, 64);
    }
    if (pp == 0) {
        const int dst = sortix[n]; // unsort
        ushort4v o;
        o.x = f2bf(xa0); o.y = f2bf(xa1); o.z = f2bf(xa2); o.w = f2bf(xa3);
        *(ushort4v*)&xb[(size_t)dst * CDIM + h * HDIM + c * 4] = o;
    }
}

// ---------------------------------------------------------------------------
extern "C" void kernel_launch(void* const* d_in, const int* in_sizes, int n_in,
                              void* d_out, int out_size, void* d_ws,
                              size_t ws_size, hipStream_t stream) {
    const float* feats  = (const float*)d_in[0];
    const float* xyz    = (const float*)d_in[1];
    const int*   index1 = (const int*)d_in[4];
    const int*   sortix = (const int*)d_in[5];
    const float* Wq = (const float*)d_in[6];
    const float* bq = (const float*)d_in[7];
    const float* Wk = (const float*)d_in[8];
    const float* bk = (const float*)d_in[9];
    const float* Wv = (const float*)d_in[10];
    const float* bv = (const float*)d_in[11];
    const float* Wp = (const float*)d_in[12];
    const float* bp = (const float*)d_in[13];
    const float* Tq = (const float*)d_in[14];
    const float* Tk = (const float*)d_in[15];
    const float* Tv = (const float*)d_in[16];
    float* out = (float*)d_out;

    char* ws = (char*)d_ws;
    size_t off = 0;
    auto alloc = [&](size_t bytes) -> void* {
        void* p = ws + off;
        off = (off + bytes + 255) & ~(size_t)255;
        return p;
    };
    unsigned short* featsbf = (unsigned short*)alloc((size_t)NPTS * CDIM * 2);
    unsigned short* Wcat    = (unsigned short*)alloc((size_t)(NQKV + CDIM) * CDIM * 2);
    float*          bcat    = (float*)alloc((NQKV + CDIM) * sizeof(float));
    unsigned short* qbf     = (unsigned short*)alloc((size_t)NH * NPTS * HDIM * 2);
    unsigned short* kh      = (unsigned short*)alloc((size_t)NH * NPTS * HDIM * 2);
    unsigned short* vh      = (unsigned short*)alloc((size_t)NH * NPTS * HDIM * 2);
    unsigned short* dq2     = (unsigned short*)alloc((size_t)NPTS * DSTR * 2);
    unsigned short* dk2     = (unsigned short*)alloc((size_t)NPTS * DSTR * 2);
    unsigned short* xb      = (unsigned short*)alloc((size_t)NPTS * CDIM * 2);
    unsigned short* Tvbf    = (unsigned short*)alloc((size_t)NL3T * NH * HDIM * 2);
    unsigned int*   pairs   = (unsigned int*)alloc((size_t)NPTS * KNB * 4);
    int*            xq      = (int*)alloc((size_t)NPTS * 3 * sizeof(int));
    unsigned int*   minbits = (unsigned int*)alloc(16);

    init_min_kernel<<<1, 64, 0, stream>>>(minbits);
    min_kernel<<<128, 256, 0, stream>>>(xyz, minbits);
    xq_kernel<<<(NPTS + 255) / 256, 256, 0, stream>>>(xyz, sortix, minbits, xq);
    relpack_kernel<<<(NPTS * KNB + 255) / 256, 256, 0, stream>>>(index1, xq, pairs);

    gather_bf16_kernel<<<(NPTS * CDIM / 4 + 255) / 256, 256, 0, stream>>>(
        feats, sortix, featsbf);
    pack_w_kernel<<<((NQKV + CDIM) * CDIM + 255) / 256, 256, 0, stream>>>(
        Wq, Wk, Wv, Wp, bq, bk, bv, bp, Wcat, bcat);
    tvpack_kernel<<<(NL3T * NH * HDIM + 255) / 256, 256, 0, stream>>>(Tv, Tvbf);

    dim3 gq(NPTS / 128, NQKV / 128);
    gemm_fused<<<gq, 256, 0, stream>>>(featsbf, Wcat, bcat, 0, qbf, kh, vh,
                                       (float*)nullptr);

    dim3 gd(NPTS / 128, NH, 2);
    dqdk_kernel<<<gd, 256, 0, stream>>>(qbf, kh, Tq, Tk, dq2, dk2);

    attn_kernel<<<NPTS, 384, 0, stream>>>(qbf, kh, vh, pairs, dq2, dk2, Tvbf,
                                          sortix, xb);

    dim3 gp(NPTS / 128, CDIM / 128);
    gemm_fused<<<gp, 256, 0, stream>>>(xb, Wcat + (size_t)NQKV * CDIM,
                                       bcat + NQKV, 1, qbf, kh, vh, out);
}

// Round 4
// 290.618 us; speedup vs baseline: 2.9961x; 1.0013x over previous
//
#include <hip/hip_runtime.h>
#include <hip/hip_bf16.h>
#include <cstdint>
#include <cstddef>

#define NPTS 16000
#define KNB  16
#define CDIM 384
#define NH   6
#define HDIM 64
#define T2C  49
#define NQKV 1152            // 3*384 fused q,k,v output cols
#define NL3T 147             // 49*3 table rows
#define DSTR 882             // 147*6 : per-point dq/dk row stride (elems)

static constexpr float WIN    = 6.0f;
static constexpr float QUANT  = 0.24f;
static constexpr float QSCALE = 0.125f; // 64^-0.5

typedef __attribute__((ext_vector_type(8))) short short8;
typedef __attribute__((ext_vector_type(4))) float floatx4;
typedef __attribute__((ext_vector_type(4))) unsigned short ushort4v;

__device__ inline unsigned short f2bf(float x) {
    unsigned int u = __float_as_uint(x);
    unsigned int r = (u + 0x7fffu + ((u >> 16) & 1u)) >> 16;
    return (unsigned short)r;
}
__device__ inline float bf2f(unsigned short b) {
    return __uint_as_float(((unsigned int)b) << 16);
}

// ---------------------------------------------------------------- min reduce
__global__ void init_min_kernel(unsigned int* minbits) {
    if (threadIdx.x < 3) minbits[threadIdx.x] = 0x7f800000u; // +inf
}

__global__ void min_kernel(const float* __restrict__ xyz,
                           unsigned int* __restrict__ minbits) {
    float m0 = INFINITY, m1 = INFINITY, m2 = INFINITY;
    for (int i = blockIdx.x * blockDim.x + threadIdx.x; i < NPTS;
         i += gridDim.x * blockDim.x) {
        m0 = fminf(m0, xyz[i * 3 + 0]);
        m1 = fminf(m1, xyz[i * 3 + 1]);
        m2 = fminf(m2, xyz[i * 3 + 2]);
    }
#pragma unroll
    for (int off = 1; off < 64; off <<= 1) {
        m0 = fminf(m0, __shfl_xor(m0, off, 64));
        m1 = fminf(m1, __shfl_xor(m1, off, 64));
        m2 = fminf(m2, __shfl_xor(m2, off, 64));
    }
    if ((threadIdx.x & 63) == 0) {
        atomicMin(&minbits[0], __float_as_uint(m0)); // xyz >= 0
        atomicMin(&minbits[1], __float_as_uint(m1));
        atomicMin(&minbits[2], __float_as_uint(m2));
    }
}

// ------------------------------------------------------------- quantize xyz
__global__ void xq_kernel(const float* __restrict__ xyz,
                          const int* __restrict__ sort_idx,
                          const unsigned int* __restrict__ minbits,
                          int* __restrict__ xq) {
    int n = blockIdx.x * blockDim.x + threadIdx.x;
    if (n >= NPTS) return;
    int orig = sort_idx[n];
#pragma unroll
    for (int t = 0; t < 3; ++t) {
        float mn = __uint_as_float(minbits[t]);
        float v  = xyz[orig * 3 + t] - mn;   // >= 0
        float md = fmodf(v, WIN);            // == np.mod for non-negative
        float q  = floorf(md / QUANT);
        xq[n * 3 + t] = (int)q;
    }
}

// ----------------------------------------------- pack (key, rel0..2) per pair
__global__ void relpack_kernel(const int* __restrict__ idx1,
                               const int* __restrict__ xq,
                               unsigned int* __restrict__ pairs) {
    int m = blockIdx.x * blockDim.x + threadIdx.x;
    if (m >= NPTS * KNB) return;
    int n = m >> 4;
    int key = idx1[m];
    int r0 = xq[n * 3 + 0] - xq[key * 3 + 0] + 24; r0 = min(max(r0, 0), T2C - 1);
    int r1 = xq[n * 3 + 1] - xq[key * 3 + 1] + 24; r1 = min(max(r1, 0), T2C - 1);
    int r2 = xq[n * 3 + 2] - xq[key * 3 + 2] + 24; r2 = min(max(r2, 0), T2C - 1);
    pairs[m] = (unsigned)key | ((unsigned)r0 << 14) | ((unsigned)r1 << 20) |
               ((unsigned)r2 << 26);
}

// ------------------------------------------------- gather+convert feats->bf16
__global__ void gather_bf16_kernel(const float* __restrict__ feats,
                                   const int* __restrict__ sortix,
                                   unsigned short* __restrict__ out) {
    int i = blockIdx.x * blockDim.x + threadIdx.x; // group of 4 elements
    if (i >= NPTS * CDIM / 4) return;
    int n  = i / (CDIM / 4);
    int c4 = (i % (CDIM / 4)) * 4;
    const float4 v = *(const float4*)&feats[(size_t)sortix[n] * CDIM + c4];
    ushort4v o;
    o.x = f2bf(v.x); o.y = f2bf(v.y); o.z = f2bf(v.z); o.w = f2bf(v.w);
    *(ushort4v*)&out[(size_t)n * CDIM + c4] = o;
}

// --------------------------------------------- pack W(q|k|v|p) -> bf16, biases
__global__ void pack_w_kernel(const float* __restrict__ Wq,
                              const float* __restrict__ Wk,
                              const float* __restrict__ Wv,
                              const float* __restrict__ Wp,
                              const float* __restrict__ bq,
                              const float* __restrict__ bk,
                              const float* __restrict__ bv,
                              const float* __restrict__ bp,
                              unsigned short* __restrict__ Wcat,
                              float* __restrict__ bcat) {
    int i = blockIdx.x * blockDim.x + threadIdx.x;
    if (i < NQKV + CDIM)
        bcat[i] = (i < 384) ? bq[i] : (i < 768) ? bk[i - 384]
                : (i < 1152) ? bv[i - 768] : bp[i - 1152];
    if (i >= (NQKV + CDIM) * CDIM) return;
    int j = i / CDIM, k = i % CDIM;
    float v = (j < 384)  ? Wq[j * CDIM + k]
            : (j < 768)  ? Wk[(j - 384) * CDIM + k]
            : (j < 1152) ? Wv[(j - 768) * CDIM + k]
                         : Wp[(j - 1152) * CDIM + k];
    Wcat[i] = f2bf(v);
}

// ----------------------------------------------------------- Tv table -> bf16
__global__ void tvpack_kernel(const float* __restrict__ Tv,
                              unsigned short* __restrict__ Tvbf) {
    int i = blockIdx.x * blockDim.x + threadIdx.x;
    if (i < NL3T * NH * HDIM) Tvbf[i] = f2bf(Tv[i]);
}

// ------------------------------------------------------ fused bf16 MFMA GEMM
// mode 0: A=featsbf [16000x384], W rows 0..1151  -> qbf (bf16,*SCALE), kh, vh
// mode 1: A=xb      [16000x384], W rows 1152..   -> outf (f32 + bias)
__global__ __launch_bounds__(256) void gemm_fused(
    const unsigned short* __restrict__ Abf,
    const unsigned short* __restrict__ Wrows,   // pre-offset
    const float* __restrict__ bias,             // pre-offset
    int mode,
    unsigned short* __restrict__ qb, unsigned short* __restrict__ kb,
    unsigned short* __restrict__ vb, float* __restrict__ outf) {
    __shared__ unsigned short As[128 * 64];
    __shared__ unsigned short Bs[128 * 64];
    const int tid  = threadIdx.x;
    const int lane = tid & 63;
    const int w    = tid >> 6;
    const int wm   = w >> 1, wn = w & 1;
    const int m0   = blockIdx.x * 128;
    const int jn0  = blockIdx.y * 128;

    floatx4 acc[4][4];
#pragma unroll
    for (int i = 0; i < 4; ++i)
#pragma unroll
        for (int j = 0; j < 4; ++j) acc[i][j] = (floatx4)0.0f;

    for (int kt = 0; kt < 6; ++kt) {
        const int k0 = kt * 64;
#pragma unroll
        for (int q = 0; q < 4; ++q) {
            const int s    = w * 4 + q;            // 1KB segment id
            const int row  = s * 8 + (lane >> 3);
            const int col  = (lane & 7) * 8;
            const unsigned short* ga = Abf   + (size_t)(m0  + row) * CDIM + k0 + col;
            const unsigned short* gb = Wrows + (size_t)(jn0 + row) * CDIM + k0 + col;
            __builtin_amdgcn_global_load_lds(
                (const __attribute__((address_space(1))) void*)ga,
                (__attribute__((address_space(3))) void*)&As[s * 512], 16, 0, 0);
            __builtin_amdgcn_global_load_lds(
                (const __attribute__((address_space(1))) void*)gb,
                (__attribute__((address_space(3))) void*)&Bs[s * 512], 16, 0, 0);
        }
        __syncthreads();
#pragma unroll
        for (int ks = 0; ks < 2; ++ks) {
            short8 a[4], b[4];
#pragma unroll
            for (int mi = 0; mi < 4; ++mi) {
                int row = wm * 64 + mi * 16 + (lane & 15);
                a[mi] = *(const short8*)&As[row * 64 + ks * 32 + (lane >> 4) * 8];
            }
#pragma unroll
            for (int ni = 0; ni < 4; ++ni) {
                int jr = wn * 64 + ni * 16 + (lane & 15);
                b[ni] = *(const short8*)&Bs[jr * 64 + ks * 32 + (lane >> 4) * 8];
            }
#pragma unroll
            for (int mi = 0; mi < 4; ++mi)
#pragma unroll
                for (int ni = 0; ni < 4; ++ni)
                    acc[mi][ni] = __builtin_amdgcn_mfma_f32_16x16x32_bf16(
                        a[mi], b[ni], acc[mi][ni], 0, 0, 0);
        }
        __syncthreads();
    }

#pragma unroll
    for (int mi = 0; mi < 4; ++mi)
#pragma unroll
        for (int ni = 0; ni < 4; ++ni) {
            int j = jn0 + wn * 64 + ni * 16 + (lane & 15);
            float bsv = bias[j];
            if (mode == 0) {
                int which = j / CDIM;
                int c = j - which * CDIM;
                int h = c >> 6, d = c & 63;
#pragma unroll
                for (int r = 0; r < 4; ++r) {
                    int n = m0 + wm * 64 + mi * 16 + (lane >> 4) * 4 + r;
                    float val = acc[mi][ni][r] + bsv;
                    size_t o = ((size_t)h * NPTS + n) * HDIM + d;
                    if (which == 0)      qb[o] = f2bf(val * QSCALE);
                    else if (which == 1) kb[o] = f2bf(val);
                    else                 vb[o] = f2bf(val);
                }
            } else {
#pragma unroll
                for (int r = 0; r < 4; ++r) {
                    int n = m0 + wm * 64 + mi * 16 + (lane >> 4) * 4 + r;
                    outf[(size_t)n * CDIM + j] = acc[mi][ni][r] + bsv;
                }
            }
        }
}

// ----------------------------------- dq/dk table-dot GEMM  [N x 64]x[64 x 147]
// X[n][j][h] (bf16) = A[h][n][:] . T[(j*6+h)*64 + :]   for j < 147
__global__ __launch_bounds__(256) void dqdk_kernel(
    const unsigned short* __restrict__ qbf, const unsigned short* __restrict__ kh,
    const float* __restrict__ Tq, const float* __restrict__ Tk,
    unsigned short* __restrict__ dq2, unsigned short* __restrict__ dk2) {
    const int h   = blockIdx.y;
    const bool isk = blockIdx.z != 0;
    const unsigned short* A = isk ? kh : qbf;
    const float* T          = isk ? Tk : Tq;
    unsigned short* X       = isk ? dk2 : dq2;

    const int lane  = threadIdx.x & 63;
    const int w     = threadIdx.x >> 6;
    const int m0    = blockIdx.x * 128 + w * 32;
    const int chunk = lane >> 4;
    const int cl    = lane & 15;

    floatx4 acc[2][10];
#pragma unroll
    for (int mi = 0; mi < 2; ++mi)
#pragma unroll
        for (int ni = 0; ni < 10; ++ni) acc[mi][ni] = (floatx4)0.0f;

#pragma unroll
    for (int ks = 0; ks < 2; ++ks) {
        short8 a[2];
#pragma unroll
        for (int mi = 0; mi < 2; ++mi)
            a[mi] = *(const short8*)&A[((size_t)h * NPTS + m0 + mi * 16 + cl) * HDIM +
                                       ks * 32 + chunk * 8];
#pragma unroll
        for (int ni = 0; ni < 10; ++ni) {
            int j = ni * 16 + cl;
            short8 b = (short8)0;
            if (j < NL3T) {
                const float* tp = &T[(size_t)(j * NH + h) * HDIM + ks * 32 + chunk * 8];
                float4 f0 = *(const float4*)tp;
                float4 f1 = *(const float4*)(tp + 4);
                b[0] = (short)f2bf(f0.x); b[1] = (short)f2bf(f0.y);
                b[2] = (short)f2bf(f0.z); b[3] = (short)f2bf(f0.w);
                b[4] = (short)f2bf(f1.x); b[5] = (short)f2bf(f1.y);
                b[6] = (short)f2bf(f1.z); b[7] = (short)f2bf(f1.w);
            }
#pragma unroll
            for (int mi = 0; mi < 2; ++mi)
                acc[mi][ni] = __builtin_amdgcn_mfma_f32_16x16x32_bf16(
                    a[mi], b, acc[mi][ni], 0, 0, 0);
        }
    }
#pragma unroll
    for (int mi = 0; mi < 2; ++mi)
#pragma unroll
        for (int ni = 0; ni < 10; ++ni) {
            int j = ni * 16 + cl;
            if (j >= NL3T) continue;
#pragma unroll
            for (int r = 0; r < 4; ++r) {
                int n = m0 + mi * 16 + chunk * 4 + r;
                X[(size_t)n * DSTR + j * 6 + h] = f2bf(acc[mi][ni][r]);
            }
        }
}

// -------------------------------------------------- fused attention per query
// grid NPTS, block 384 = 6 waves; wave h = head h of query blockIdx.x.
// lane = pp*16 + c : pp selects pair-in-group, c selects d-chunk (4 d).
__global__ __launch_bounds__(384) void attn_kernel(
    const unsigned short* __restrict__ qbf, const unsigned short* __restrict__ kh,
    const unsigned short* __restrict__ vh,
    const unsigned int* __restrict__ pairs,
    const unsigned short* __restrict__ dq2, const unsigned short* __restrict__ dk2,
    const unsigned short* __restrict__ Tvbf,
    const int* __restrict__ sortix,
    unsigned short* __restrict__ xb) {
    const int n    = blockIdx.x;
    const int h    = threadIdx.x >> 6;
    const int lane = threadIdx.x & 63;
    const int pp   = lane >> 4, c = lane & 15;

    const ushort4v q4 = *(const ushort4v*)&qbf[((size_t)h * NPTS + n) * HDIM + c * 4];
    const float qx = bf2f(q4.x), qy = bf2f(q4.y), qz = bf2f(q4.z), qw = bf2f(q4.w);

    const unsigned short* dqb = dq2 + (size_t)n * DSTR + h;

    unsigned int pv[4];
#pragma unroll
    for (int g = 0; g < 4; ++g) pv[g] = pairs[n * KNB + g * 4 + pp];

    int keyg[4], j0g[4], j1g[4], j2g[4];
#pragma unroll
    for (int g = 0; g < 4; ++g) {
        keyg[g] = (int)(pv[g] & 0x3FFFu);
        j0g[g]  = (int)((pv[g] >> 14) & 63u) * 18;
        j1g[g]  = (int)((pv[g] >> 20) & 63u) * 18 + 6;
        j2g[g]  = (int)(pv[g] >> 26) * 18 + 12;
    }

    float tab[4];
#pragma unroll
    for (int g = 0; g < 4; ++g) {
        const unsigned short* dkb = dk2 + (size_t)keyg[g] * DSTR + h;
        tab[g] = bf2f(dqb[j0g[g]]) + bf2f(dqb[j1g[g]]) + bf2f(dqb[j2g[g]]) +
                 bf2f(dkb[j0g[g]]) + bf2f(dkb[j1g[g]]) + bf2f(dkb[j2g[g]]);
    }

    float lg[4];
#pragma unroll
    for (int g = 0; g < 4; ++g) {
        const ushort4v k4 =
            *(const ushort4v*)&kh[((size_t)h * NPTS + keyg[g]) * HDIM + c * 4];
        lg[g] = qx * bf2f(k4.x) + qy * bf2f(k4.y) + qz * bf2f(k4.z) + qw * bf2f(k4.w);
    }
#pragma unroll
    for (int m = 1; m <= 8; m <<= 1)
#pragma unroll
        for (int g = 0; g < 4; ++g) lg[g] += __shfl_xor(lg[g], m, 64);
#pragma unroll
    for (int g = 0; g < 4; ++g) lg[g] += tab[g];

    // softmax over 16 pairs (4 in-lane x 4 pp-groups)
    float mx = fmaxf(fmaxf(lg[0], lg[1]), fmaxf(lg[2], lg[3]));
    mx = fmaxf(mx, __shfl_xor(mx, 16, 64));
    mx = fmaxf(mx, __shfl_xor(mx, 32, 64));
    float e[4], s = 0.f;
#pragma unroll
    for (int g = 0; g < 4; ++g) { e[g] = expf(lg[g] - mx); s += e[g]; }
    s += __shfl_xor(s, 16, 64);
    s += __shfl_xor(s, 32, 64);
    const float inv = 1.f / s;

    float xa0 = 0.f, xa1 = 0.f, xa2 = 0.f, xa3 = 0.f;
#pragma unroll
    for (int g = 0; g < 4; ++g) {
        const float wgt = e[g] * inv;
        const ushort4v v4 =
            *(const ushort4v*)&vh[((size_t)h * NPTS + keyg[g]) * HDIM + c * 4];
        const ushort4v t0 = *(const ushort4v*)&Tvbf[(size_t)(j0g[g] + h) * HDIM + c * 4];
        const ushort4v t1 = *(const ushort4v*)&Tvbf[(size_t)(j1g[g] + h) * HDIM + c * 4];
        const ushort4v t2 = *(const ushort4v*)&Tvbf[(size_t)(j2g[g] + h) * HDIM + c * 4];
        xa0 += wgt * (bf2f(v4.x) + bf2f(t0.x) + bf2f(t1.x) + bf2f(t2.x));
        xa1 += wgt * (bf2f(v4.y) + bf2f(t0.y) + bf2f(t1.y) + bf2f(t2.y));
        xa2 += wgt * (bf2f(v4.z) + bf2f(t0.z) + bf2f(t1.z) + bf2f(t2.z));
        xa3 += wgt * (bf2f(v4.w) + bf2f(t0.w) + bf2f(t1.w) + bf2f(t2.w));
    }
#pragma unroll
    for (int m = 16; m <= 32; m <<= 1) {
        xa0 += __shfl_xor(xa0, m, 64);
        xa1 += __shfl_xor(xa1, m, 64);
        xa2 += __shfl_xor(xa2, m, 64);
        xa3 += __shfl_xor(xa3, m, 64);
    }
    if (pp == 0) {
        const int dst = sortix[n]; // unsort
        ushort4v o;
        o.x = f2bf(xa0); o.y = f2bf(xa1); o.z = f2bf(xa2); o.w = f2bf(xa3);
        *(ushort4v*)&xb[(size_t)dst * CDIM + h * HDIM + c * 4] = o;
    }
}

// ---------------------------------------------------------------------------
extern "C" void kernel_launch(void* const* d_in, const int* in_sizes, int n_in,
                              void* d_out, int out_size, void* d_ws,
                              size_t ws_size, hipStream_t stream) {
    const float* feats  = (const float*)d_in[0];
    const float* xyz    = (const float*)d_in[1];
    const int*   index1 = (const int*)d_in[4];
    const int*   sortix = (const int*)d_in[5];
    const float* Wq = (const float*)d_in[6];
    const float* bq = (const float*)d_in[7];
    const float* Wk = (const float*)d_in[8];
    const float* bk = (const float*)d_in[9];
    const float* Wv = (const float*)d_in[10];
    const float* bv = (const float*)d_in[11];
    const float* Wp = (const float*)d_in[12];
    const float* bp = (const float*)d_in[13];
    const float* Tq = (const float*)d_in[14];
    const float* Tk = (const float*)d_in[15];
    const float* Tv = (const float*)d_in[16];
    float* out = (float*)d_out;

    char* ws = (char*)d_ws;
    size_t off = 0;
    auto alloc = [&](size_t bytes) -> void* {
        void* p = ws + off;
        off = (off + bytes + 255) & ~(size_t)255;
        return p;
    };
    unsigned short* featsbf = (unsigned short*)alloc((size_t)NPTS * CDIM * 2);
    unsigned short* Wcat    = (unsigned short*)alloc((size_t)(NQKV + CDIM) * CDIM * 2);
    float*          bcat    = (float*)alloc((NQKV + CDIM) * sizeof(float));
    unsigned short* qbf     = (unsigned short*)alloc((size_t)NH * NPTS * HDIM * 2);
    unsigned short* kh      = (unsigned short*)alloc((size_t)NH * NPTS * HDIM * 2);
    unsigned short* vh      = (unsigned short*)alloc((size_t)NH * NPTS * HDIM * 2);
    unsigned short* dq2     = (unsigned short*)alloc((size_t)NPTS * DSTR * 2);
    unsigned short* dk2     = (unsigned short*)alloc((size_t)NPTS * DSTR * 2);
    unsigned short* xb      = (unsigned short*)alloc((size_t)NPTS * CDIM * 2);
    unsigned short* Tvbf    = (unsigned short*)alloc((size_t)NL3T * NH * HDIM * 2);
    unsigned int*   pairs   = (unsigned int*)alloc((size_t)NPTS * KNB * 4);
    int*            xq      = (int*)alloc((size_t)NPTS * 3 * sizeof(int));
    unsigned int*   minbits = (unsigned int*)alloc(16);

    init_min_kernel<<<1, 64, 0, stream>>>(minbits);
    min_kernel<<<128, 256, 0, stream>>>(xyz, minbits);
    xq_kernel<<<(NPTS + 255) / 256, 256, 0, stream>>>(xyz, sortix, minbits, xq);
    relpack_kernel<<<(NPTS * KNB + 255) / 256, 256, 0, stream>>>(index1, xq, pairs);

    gather_bf16_kernel<<<(NPTS * CDIM / 4 + 255) / 256, 256, 0, stream>>>(
        feats, sortix, featsbf);
    pack_w_kernel<<<((NQKV + CDIM) * CDIM + 255) / 256, 256, 0, stream>>>(
        Wq, Wk, Wv, Wp, bq, bk, bv, bp, Wcat, bcat);
    tvpack_kernel<<<(NL3T * NH * HDIM + 255) / 256, 256, 0, stream>>>(Tv, Tvbf);

    dim3 gq(NPTS / 128, NQKV / 128);
    gemm_fused<<<gq, 256, 0, stream>>>(featsbf, Wcat, bcat, 0, qbf, kh, vh,
                                       (float*)nullptr);

    dim3 gd(NPTS / 128, NH, 2);
    dqdk_kernel<<<gd, 256, 0, stream>>>(qbf, kh, Tq, Tk, dq2, dk2);

    attn_kernel<<<NPTS, 384, 0, stream>>>(qbf, kh, vh, pairs, dq2, dk2, Tvbf,
                                          sortix, xb);

    dim3 gp(NPTS / 128, CDIM / 128);
    gemm_fused<<<gp, 256, 0, stream>>>(xb, Wcat + (size_t)NQKV * CDIM,
                                       bcat + NQKV, 1, qbf, kh, vh, out);
}